// Round 4
// baseline (307.518 us; speedup 1.0000x reference)
//
#include <hip/hip_runtime.h>
#include <math.h>

#define E_TOT   640000
#define NN      20000
#define DIM     128
#define EDGE_DIM 16

typedef float f32x4 __attribute__((ext_vector_type(4)));
typedef float f32x2 __attribute__((ext_vector_type(2)));
typedef short s16x8 __attribute__((ext_vector_type(8)));
typedef unsigned u32x4 __attribute__((ext_vector_type(4)));
typedef __bf16 bfx8 __attribute__((ext_vector_type(8)));

__device__ __forceinline__ unsigned short f2bf(float f) {
    unsigned u = __builtin_bit_cast(unsigned, f);
    u += 0x7fffu + ((u >> 16) & 1u);
    return (unsigned short)(u >> 16);
}
__device__ __forceinline__ unsigned cvt_pk_bf16(float lo, float hi) {
    unsigned r;
    asm("v_cvt_pk_bf16_f32 %0, %1, %2" : "=v"(r) : "v"(lo), "v"(hi));
    return r;
}
__device__ __forceinline__ float silu_f(float x)    { return x / (1.0f + __expf(-x)); }
__device__ __forceinline__ float sigmoid_f(float x) { return 1.0f / (1.0f + __expf(-x)); }

#define MFMA16(a, b, c) __builtin_amdgcn_mfma_f32_16x16x32_bf16( \
    __builtin_bit_cast(bfx8, (a)), __builtin_bit_cast(bfx8, (b)), (c), 0, 0, 0)

// ---------------------------------------------------------------------------
// prep kernels
// ---------------------------------------------------------------------------
__global__ void prep_h_kernel(const float* __restrict__ h,
                              unsigned short* __restrict__ h_bf, int n4) {
    int i = blockIdx.x * blockDim.x + threadIdx.x;
    if (i < n4) {
        float4 v = reinterpret_cast<const float4*>(h)[i];
        unsigned short* d = h_bf + i * 4;
        d[0] = f2bf(v.x); d[1] = f2bf(v.y); d[2] = f2bf(v.z); d[3] = f2bf(v.w);
    }
}

// pack W[K][128] f32 -> fragment-major bf16, K padded, COLUMN-PAIR permuted:
// packed pos (sg, f, q, t) holds W[k = sg*8+t][col = (f>>1)*32 + 2*q + (f&1)].
// MFMA B-frag nj of wave w then covers columns {w*32 + 2q + nj}.
__global__ void prep_w_kernel(const float* __restrict__ W,
                              unsigned short* __restrict__ Wp,
                              int K, int tot) {   // tot = Kp*128
    int id = blockIdx.x * blockDim.x + threadIdx.x;
    if (id >= tot) return;
    int t   = id & 7;
    int pos = (id >> 3) & 127;      // f*16 + q
    int sg  = id >> 10;
    int q = pos & 15, f = pos >> 4;
    int col = (f >> 1) * 32 + 2 * q + (f & 1);
    int k = sg * 8 + t;
    Wp[id] = (k < K) ? f2bf(W[(size_t)k * DIM + col]) : (unsigned short)0;
}

// ---------------------------------------------------------------------------
// counting sort of edges by row
// ---------------------------------------------------------------------------
__global__ void hist_kernel(const int* __restrict__ ei, int* __restrict__ counts) {
    int e = blockIdx.x * blockDim.x + threadIdx.x;
    if (e < E_TOT) atomicAdd(&counts[ei[e]], 1);
}

__global__ __launch_bounds__(1024) void scan_kernel(int* __restrict__ counts) {
    __shared__ int s[1024];
    const int tid = threadIdx.x;
    const int CH = 20;
    int base = tid * CH;
    int loc[CH];
    int sum = 0;
    #pragma unroll
    for (int i = 0; i < CH; ++i) {
        int idx = base + i;
        loc[i] = (idx < NN) ? counts[idx] : 0;
        sum += loc[i];
    }
    s[tid] = sum;
    __syncthreads();
    for (int off = 1; off < 1024; off <<= 1) {
        int v = (tid >= off) ? s[tid - off] : 0;
        __syncthreads();
        s[tid] += v;
        __syncthreads();
    }
    int run = s[tid] - sum;
    #pragma unroll
    for (int i = 0; i < CH; ++i) {
        int idx = base + i;
        if (idx < NN) counts[idx] = run;
        run += loc[i];
    }
}

__global__ void scatter_kernel(const int* __restrict__ ei, int* __restrict__ cursor,
                               int* __restrict__ eidS, unsigned short* __restrict__ rowS) {
    int e = blockIdx.x * blockDim.x + threadIdx.x;
    if (e < E_TOT) {
        int r = ei[e];
        int p = atomicAdd(&cursor[r], 1);
        eidS[p] = e;
        rowS[p] = (unsigned short)r;
    }
}

// ---------------------------------------------------------------------------
// Edge kernel: 64 edge-slots/block, 4 waves, wave w owns cols [32w,32w+32)
// as pairs (2q, 2q+1). A-fragments loaded directly from global; only ea is
// LDS-staged. Messages -> bf16-packed LDS; wave-uniform segmented reduction.
// LDS union timeline: s_ea (L1) -> s_H (L2) -> s_msgP (reduction).
// ---------------------------------------------------------------------------
template<bool SORTED>
__global__ __launch_bounds__(256, 8) void edge_kernel(
    const unsigned short* __restrict__ h_bf,
    const int* __restrict__ ei,
    const int* __restrict__ eidS,
    const unsigned short* __restrict__ rowS,
    const float* __restrict__ ea,
    const float* __restrict__ emask,
    const unsigned short* __restrict__ W1p,  // 288x128 packed (permuted)
    const float* __restrict__ bm1,
    const unsigned short* __restrict__ W2p,  // 128x128 packed (permuted)
    const float* __restrict__ bm2,
    const float* __restrict__ Wa, const float* __restrict__ ba,
    float* __restrict__ agg)
{
    __shared__ __align__(16) unsigned char s_u[17408];
    auto s_ea   = reinterpret_cast<unsigned short(*)[40]>(s_u);   //  5120 B
    auto s_H    = reinterpret_cast<unsigned short(*)[136]>(s_u);  // 17408 B
    auto s_msgP = reinterpret_cast<unsigned(*)[66]>(s_u);         // 16896 B
    __shared__ int   s_eid[64];
    __shared__ int   s_row[64];
    __shared__ int   s_col[64];
    __shared__ float s_mask[64];
    __shared__ float s_att[64];

    const int tid = threadIdx.x;
    const int e0  = blockIdx.x * 64;
    const int q   = tid & 15;
    const int g   = (tid >> 4) & 3;
    const int wn0 = (tid >> 6) * 32;

    if (tid < 64) {
        int e = SORTED ? eidS[e0 + tid] : (e0 + tid);
        s_eid[tid]  = e;
        s_row[tid]  = SORTED ? (int)rowS[e0 + tid] : ei[e];
        s_col[tid]  = ei[E_TOT + e];
        s_mask[tid] = emask[e];
        s_att[tid]  = 0.f;
    }
    __syncthreads();

    // stage edge_attr -> s_ea (bf16): waves 0,1
    if (tid < 128) {
        int sl = tid >> 1, hf = tid & 1;
        const float4* pe = reinterpret_cast<const float4*>(
            ea + (size_t)s_eid[sl] * EDGE_DIM + hf * 8);
        float4 u = pe[0], v = pe[1];
        unsigned* d = reinterpret_cast<unsigned*>(&s_ea[sl][hf * 8]);
        d[0] = cvt_pk_bf16(u.x, u.y);
        d[1] = cvt_pk_bf16(u.z, u.w);
        d[2] = cvt_pk_bf16(v.x, v.y);
        d[3] = cvt_pk_bf16(v.z, v.w);
    }

    // per-mi node byte offsets into h_bf
    unsigned rbo[4], cbo[4];
    #pragma unroll
    for (int mi = 0; mi < 4; ++mi) {
        rbo[mi] = (unsigned)s_row[mi * 16 + q] * (DIM * 2);
        cbo[mi] = (unsigned)s_col[mi * 16 + q] * (DIM * 2);
    }
    const char* hb8 = reinterpret_cast<const char*>(h_bf);

    f32x4 acc[4][2];
    #pragma unroll
    for (int mi = 0; mi < 4; ++mi) {
        acc[mi][0] = (f32x4)0.f;
        acc[mi][1] = (f32x4)0.f;
    }

    // ---------------- layer 1, s = 0..7 (h[row] | h[col]) ----------------
    #pragma unroll
    for (int s = 0; s < 8; ++s) {
        const int boff = (s & 3) * 64 + g * 16;   // byte offset within node row
        s16x8 b0 = *reinterpret_cast<const s16x8*>(W1p + ((s * 4 + g) * DIM + wn0 + q) * 8);
        s16x8 b1 = *reinterpret_cast<const s16x8*>(W1p + ((s * 4 + g) * DIM + wn0 + 16 + q) * 8);
        #pragma unroll
        for (int mi = 0; mi < 4; ++mi) {
            unsigned off = ((s < 4) ? rbo[mi] : cbo[mi]) + boff;
            s16x8 a = *reinterpret_cast<const s16x8*>(hb8 + off);
            acc[mi][0] = MFMA16(a, b0, acc[mi][0]);
            acc[mi][1] = MFMA16(a, b1, acc[mi][1]);
        }
    }
    __syncthreads();   // s_ea staged by waves 0,1 is now visible

    // ---------------- layer 1, s = 8 (edge_attr + zero pad) ----------------
    {
        s16x8 b0 = *reinterpret_cast<const s16x8*>(W1p + ((32 + g) * DIM + wn0 + q) * 8);
        s16x8 b1 = *reinterpret_cast<const s16x8*>(W1p + ((32 + g) * DIM + wn0 + 16 + q) * 8);
        #pragma unroll
        for (int mi = 0; mi < 4; ++mi) {
            s16x8 a = (s16x8)0;
            if (g < 2)
                a = *reinterpret_cast<const s16x8*>(&s_ea[mi * 16 + q][g * 8]);
            acc[mi][0] = MFMA16(a, b0, acc[mi][0]);
            acc[mi][1] = MFMA16(a, b1, acc[mi][1]);
        }
    }
    __syncthreads();   // s_ea dead; union becomes s_H

    // bias + silu -> s_H (packed pair write)
    {
        const f32x2 b1v = *reinterpret_cast<const f32x2*>(bm1 + wn0 + 2 * q);
        #pragma unroll
        for (int mi = 0; mi < 4; ++mi)
            #pragma unroll
            for (int r = 0; r < 4; ++r) {
                float v0 = silu_f(acc[mi][0][r] + b1v.x);
                float v1 = silu_f(acc[mi][1][r] + b1v.y);
                *reinterpret_cast<unsigned*>(&s_H[mi * 16 + g * 4 + r][wn0 + 2 * q]) =
                    cvt_pk_bf16(v0, v1);
            }
    }
    __syncthreads();

    // ---------------- layer 2 ----------------
    #pragma unroll
    for (int mi = 0; mi < 4; ++mi) {
        acc[mi][0] = (f32x4)0.f;
        acc[mi][1] = (f32x4)0.f;
    }
    #pragma unroll
    for (int s = 0; s < 4; ++s) {
        s16x8 b0 = *reinterpret_cast<const s16x8*>(W2p + ((s * 4 + g) * DIM + wn0 + q) * 8);
        s16x8 b1 = *reinterpret_cast<const s16x8*>(W2p + ((s * 4 + g) * DIM + wn0 + 16 + q) * 8);
        #pragma unroll
        for (int mi = 0; mi < 4; ++mi) {
            s16x8 a = *reinterpret_cast<const s16x8*>(&s_H[mi * 16 + q][s * 32 + g * 8]);
            acc[mi][0] = MFMA16(a, b0, acc[mi][0]);
            acc[mi][1] = MFMA16(a, b1, acc[mi][1]);
        }
    }

    // bias + silu; attention partial dot, reduce across the 16 q-lanes
    {
        const f32x2 b2v = *reinterpret_cast<const f32x2*>(bm2 + wn0 + 2 * q);
        const f32x2 wav = *reinterpret_cast<const f32x2*>(Wa + wn0 + 2 * q);
        #pragma unroll
        for (int mi = 0; mi < 4; ++mi)
            #pragma unroll
            for (int r = 0; r < 4; ++r) {
                float v0 = silu_f(acc[mi][0][r] + b2v.x);
                float v1 = silu_f(acc[mi][1][r] + b2v.y);
                acc[mi][0][r] = v0; acc[mi][1][r] = v1;
                float p = v0 * wav.x + v1 * wav.y;
                p += __shfl_xor(p, 1, 64);
                p += __shfl_xor(p, 2, 64);
                p += __shfl_xor(p, 4, 64);
                p += __shfl_xor(p, 8, 64);
                if (q == 0) atomicAdd(&s_att[mi * 16 + g * 4 + r], p);
            }
    }
    __syncthreads();   // s_att complete; s_H dead

    // scale factors (64 threads) + unscaled bf16-packed messages (all threads)
    if (tid < 64)
        s_att[tid] = sigmoid_f(s_att[tid] + ba[0]) * s_mask[tid];
    #pragma unroll
    for (int mi = 0; mi < 4; ++mi)
        #pragma unroll
        for (int r = 0; r < 4; ++r) {
            int e = mi * 16 + g * 4 + r;
            s_msgP[e][(wn0 >> 1) + q] = cvt_pk_bf16(acc[mi][0][r], acc[mi][1][r]);
        }
    __syncthreads();

    // segmented reduction: wave wv owns edges [16wv,16wv+16), lane owns col-pair
    {
        const int wv = tid >> 6;
        const int cp = tid & 63;
        int i0 = tid & 63;
        bool bnd = (i0 == 63) || (s_row[i0] != s_row[i0 + 1]);
        unsigned long long bmask = __ballot(bnd);
        float sum0 = 0.f, sum1 = 0.f;
        #pragma unroll
        for (int j = 0; j < 16; ++j) {
            int e = wv * 16 + j;
            float sc = s_att[e];                      // uniform -> broadcast
            unsigned v = s_msgP[e][cp];
            sum0 = fmaf(__builtin_bit_cast(float, v << 16), sc, sum0);
            sum1 = fmaf(__builtin_bit_cast(float, v & 0xffff0000u), sc, sum1);
            if (((bmask >> e) & 1ull) || j == 15) {   // wave-uniform branch
                int r = s_row[e];
                float* dst = agg + (size_t)r * DIM + cp * 2;
                atomicAdd(dst, sum0);
                atomicAdd(dst + 1, sum1);
                sum0 = 0.f; sum1 = 0.f;
            }
        }
    }
}

// ---------------------------------------------------------------------------
// Node kernel: [h | agg] @ Wn1 -> silu -> @Wn2 -> residual -> flags
// Direct A-fragment loads (consecutive nodes), pair-permuted weights.
// ---------------------------------------------------------------------------
__global__ __launch_bounds__(256, 4) void node_kernel(
    const unsigned short* __restrict__ h_bf,
    const float* __restrict__ agg,
    const float* __restrict__ h,
    const float* __restrict__ flags,
    const unsigned short* __restrict__ Wn1p,  // 256x128 packed (permuted)
    const float* __restrict__ bn1,
    const unsigned short* __restrict__ Wn2p,  // 128x128 packed (permuted)
    const float* __restrict__ bn2,
    float* __restrict__ out)
{
    __shared__ __align__(16) unsigned short s_H[64][136];

    const int tid = threadIdx.x;
    const int nb0 = blockIdx.x * 64;
    const int q   = tid & 15;
    const int g   = (tid >> 4) & 3;
    const int wn0 = (tid >> 6) * 32;

    int nrow[4];
    #pragma unroll
    for (int mi = 0; mi < 4; ++mi) {
        int n = nb0 + mi * 16 + q;
        nrow[mi] = (n < NN) ? n : (NN - 1);   // clamp: garbage rows are store-masked
    }

    f32x4 acc[4][2];
    #pragma unroll
    for (int mi = 0; mi < 4; ++mi) { acc[mi][0] = (f32x4)0.f; acc[mi][1] = (f32x4)0.f; }

    // s = 0..3: h_bf (bf16 direct)
    #pragma unroll
    for (int s = 0; s < 4; ++s) {
        s16x8 b0 = *reinterpret_cast<const s16x8*>(Wn1p + ((s * 4 + g) * DIM + wn0 + q) * 8);
        s16x8 b1 = *reinterpret_cast<const s16x8*>(Wn1p + ((s * 4 + g) * DIM + wn0 + 16 + q) * 8);
        #pragma unroll
        for (int mi = 0; mi < 4; ++mi) {
            s16x8 a = *reinterpret_cast<const s16x8*>(
                h_bf + (size_t)nrow[mi] * DIM + s * 32 + g * 8);
            acc[mi][0] = MFMA16(a, b0, acc[mi][0]);
            acc[mi][1] = MFMA16(a, b1, acc[mi][1]);
        }
    }
    // s = 4..7: agg (f32 -> bf16 in-register)
    #pragma unroll
    for (int s = 4; s < 8; ++s) {
        s16x8 b0 = *reinterpret_cast<const s16x8*>(Wn1p + ((s * 4 + g) * DIM + wn0 + q) * 8);
        s16x8 b1 = *reinterpret_cast<const s16x8*>(Wn1p + ((s * 4 + g) * DIM + wn0 + 16 + q) * 8);
        #pragma unroll
        for (int mi = 0; mi < 4; ++mi) {
            const float4* pa = reinterpret_cast<const float4*>(
                agg + (size_t)nrow[mi] * DIM + (s - 4) * 32 + g * 8);
            float4 u = pa[0], v = pa[1];
            u32x4 pk;
            pk[0] = cvt_pk_bf16(u.x, u.y); pk[1] = cvt_pk_bf16(u.z, u.w);
            pk[2] = cvt_pk_bf16(v.x, v.y); pk[3] = cvt_pk_bf16(v.z, v.w);
            s16x8 a = __builtin_bit_cast(s16x8, pk);
            acc[mi][0] = MFMA16(a, b0, acc[mi][0]);
            acc[mi][1] = MFMA16(a, b1, acc[mi][1]);
        }
    }

    {
        const f32x2 b1v = *reinterpret_cast<const f32x2*>(bn1 + wn0 + 2 * q);
        #pragma unroll
        for (int mi = 0; mi < 4; ++mi)
            #pragma unroll
            for (int r = 0; r < 4; ++r) {
                float v0 = silu_f(acc[mi][0][r] + b1v.x);
                float v1 = silu_f(acc[mi][1][r] + b1v.y);
                *reinterpret_cast<unsigned*>(&s_H[mi * 16 + g * 4 + r][wn0 + 2 * q]) =
                    cvt_pk_bf16(v0, v1);
            }
    }
    __syncthreads();

    #pragma unroll
    for (int mi = 0; mi < 4; ++mi) { acc[mi][0] = (f32x4)0.f; acc[mi][1] = (f32x4)0.f; }

    #pragma unroll
    for (int s = 0; s < 4; ++s) {
        s16x8 b0 = *reinterpret_cast<const s16x8*>(Wn2p + ((s * 4 + g) * DIM + wn0 + q) * 8);
        s16x8 b1 = *reinterpret_cast<const s16x8*>(Wn2p + ((s * 4 + g) * DIM + wn0 + 16 + q) * 8);
        #pragma unroll
        for (int mi = 0; mi < 4; ++mi) {
            s16x8 a = *reinterpret_cast<const s16x8*>(&s_H[mi * 16 + q][s * 32 + g * 8]);
            acc[mi][0] = MFMA16(a, b0, acc[mi][0]);
            acc[mi][1] = MFMA16(a, b1, acc[mi][1]);
        }
    }

    {
        const f32x2 b2v = *reinterpret_cast<const f32x2*>(bn2 + wn0 + 2 * q);
        #pragma unroll
        for (int mi = 0; mi < 4; ++mi)
            #pragma unroll
            for (int r = 0; r < 4; ++r) {
                int n = nb0 + mi * 16 + g * 4 + r;
                if (n < NN) {
                    float fl = flags[n];
                    size_t b = (size_t)n * DIM + wn0 + 2 * q;
                    f32x2 hv = *reinterpret_cast<const f32x2*>(h + b);
                    f32x2 o;
                    o.x = (hv.x + acc[mi][0][r] + b2v.x) * fl;
                    o.y = (hv.y + acc[mi][1][r] + b2v.y) * fl;
                    *reinterpret_cast<f32x2*>(out + b) = o;
                }
            }
    }
}

extern "C" void kernel_launch(void* const* d_in, const int* in_sizes, int n_in,
                              void* d_out, int out_size, void* d_ws, size_t ws_size,
                              hipStream_t stream) {
    const float* h     = (const float*)d_in[0];
    const int*   ei    = (const int*)  d_in[1];
    const float* ea    = (const float*)d_in[2];
    const float* flags = (const float*)d_in[3];
    const float* emask = (const float*)d_in[4];
    const float* Wm1   = (const float*)d_in[5];
    const float* bm1   = (const float*)d_in[6];
    const float* Wm2   = (const float*)d_in[7];
    const float* bm2   = (const float*)d_in[8];
    const float* Wa    = (const float*)d_in[9];
    const float* ba    = (const float*)d_in[10];
    const float* Wn1   = (const float*)d_in[11];
    const float* bn1   = (const float*)d_in[12];
    const float* Wn2   = (const float*)d_in[13];
    const float* bn2   = (const float*)d_in[14];
    float* out = (float*)d_out;

    char* ws = (char*)d_ws;
    float*          agg   = (float*)         (ws);                 // 10,240,000
    unsigned short* h_bf  = (unsigned short*)(ws + 10240000);      //  5,120,000
    unsigned short* W1p   = (unsigned short*)(ws + 15360000);      //     73,728
    unsigned short* W2p   = (unsigned short*)(ws + 15433728);      //     32,768
    unsigned short* Wn1p  = (unsigned short*)(ws + 15466496);      //     65,536
    unsigned short* Wn2p  = (unsigned short*)(ws + 15532032);      //     32,768
    int*            cnts  = (int*)           (ws + 15564800);      //     80,000
    int*            eidS  = (int*)           (ws + 15644800);      //  2,560,000
    unsigned short* rowS  = (unsigned short*)(ws + 18204800);      //  1,280,000
    const size_t WS_NEED = 19484800;

    const bool sorted = (ws_size >= WS_NEED);

    hipMemsetAsync(agg, 0, (size_t)NN * DIM * sizeof(float), stream);
    prep_h_kernel<<<(NN * DIM / 4 + 255) / 256, 256, 0, stream>>>(h, h_bf, NN * DIM / 4);
    prep_w_kernel<<<(288 * 128 + 255) / 256, 256, 0, stream>>>(Wm1, W1p, 272, 288 * 128);
    prep_w_kernel<<<(128 * 128 + 255) / 256, 256, 0, stream>>>(Wm2, W2p, 128, 128 * 128);
    prep_w_kernel<<<(256 * 128 + 255) / 256, 256, 0, stream>>>(Wn1, Wn1p, 256, 256 * 128);
    prep_w_kernel<<<(128 * 128 + 255) / 256, 256, 0, stream>>>(Wn2, Wn2p, 128, 128 * 128);

    if (sorted) {
        hipMemsetAsync(cnts, 0, NN * sizeof(int), stream);
        hist_kernel<<<(E_TOT + 255) / 256, 256, 0, stream>>>(ei, cnts);
        scan_kernel<<<1, 1024, 0, stream>>>(cnts);
        scatter_kernel<<<(E_TOT + 255) / 256, 256, 0, stream>>>(ei, cnts, eidS, rowS);
        edge_kernel<true><<<E_TOT / 64, 256, 0, stream>>>(
            h_bf, ei, eidS, rowS, ea, emask, W1p, bm1, W2p, bm2, Wa, ba, agg);
    } else {
        edge_kernel<false><<<E_TOT / 64, 256, 0, stream>>>(
            h_bf, ei, eidS, rowS, ea, emask, W1p, bm1, W2p, bm2, Wa, ba, agg);
    }

    node_kernel<<<(NN + 63) / 64, 256, 0, stream>>>(h_bf, agg, h, flags,
                                                    Wn1p, bn1, Wn2p, bn2, out);
}